// Round 13
// baseline (326.099 us; speedup 1.0000x reference)
//
#include <hip/hip_runtime.h>
#include <hip/hip_bf16.h>
#include <math.h>

// MagNet round 13 (= round 11/12 resubmit after acquisition timeouts):
// barrier-free register-streamed fused layer.
// Diagnosis from round 10: per-step __syncthreads drained vmcnt(0) ->
// latency serialization (MfmaUtil 11%, all pipes idle). Waves split N, so
// B has no cross-wave reuse -> LDS staging was pure overhead. Now both A
// (L fp32, split to bf16x2 in VALU) and B (pre-split bf16 planes) stream
// straight into MFMA fragments from global/L2/L3; NO barriers in K-loop.
// LDS only holds the T hand-off between stage 1 and stage 2.
// Layer 2 fuses the node-mean readout (shfl reduce -> partials).
#define B_SZ   32
#define N_SZ   512
#define F_SZ   128

typedef __attribute__((ext_vector_type(8))) short short8v;
typedef __attribute__((ext_vector_type(4))) short short4v;
typedef __attribute__((ext_vector_type(4))) float f32x4;

#define MFMA16(a, bb, c) __builtin_amdgcn_mfma_f32_16x16x32_bf16((a), (bb), (c), 0, 0, 0)

__device__ __forceinline__ short bfh(float v) {
    __hip_bfloat16 h = __float2bfloat16(v);   // RN
    return __builtin_bit_cast(short, h);
}
__device__ __forceinline__ float bf2f(short s) {
    unsigned u = ((unsigned)(unsigned short)s) << 16;
    return __builtin_bit_cast(float, u);
}
__device__ __forceinline__ void split1(float v, short& h, short& l) {
    short hs = bfh(v);
    h = hs;
    l = bfh(v - bf2f(hs));
}
__device__ __forceinline__ void splitpack(const float4& a, const float4& b,
                                          short8v& h, short8v& l) {
    const float va[8] = {a.x, a.y, a.z, a.w, b.x, b.y, b.z, b.w};
    #pragma unroll
    for (int j = 0; j < 8; ++j) {
        short hs, ls;
        split1(va[j], hs, ls);
        h[j] = hs; l[j] = ls;
    }
}

// ---------------------------------------------------------------------------
// Fused layer: h_out = crelu( (L @ h_in) @ W )   complex, bf16x3.
// h_in: transposed bf16 planes [B][128 f][512 node] (rh,rl[,ih,il]).
// W planes: [128 out][128 f]. LAST=0: write h_out planes (same layout).
// LAST=1: fuse readout -> part[(b*16+rb)*256 + {f, 128+f}] = sum over the
// block's 32 nodes of {Re,Im} h_out (mean finished in head_kernel).
// Grid 512 blocks (16 row-blocks x 32 batches, XCD-remapped), 256 thr/4 waves.
// ---------------------------------------------------------------------------
template<int HAS_BIM, int LAST>
__global__ __launch_bounds__(256, 2)
void fused_layer(const float* __restrict__ Lre, const float* __restrict__ Lim,
                 const short* __restrict__ Brh, const short* __restrict__ Brl,
                 const short* __restrict__ Bih, const short* __restrict__ Bil,
                 const short* __restrict__ Wrh, const short* __restrict__ Wrl,
                 const short* __restrict__ Wih, const short* __restrict__ Wil,
                 short* __restrict__ Orh, short* __restrict__ Orl,
                 short* __restrict__ Oih, short* __restrict__ Oil,
                 float* __restrict__ part)
{
    __shared__ short Ts[4][32 * 136];       // T hand-off planes (34.8 KB)

    const int t = threadIdx.x;
    // XCD-bijective remap: blocks of one batch share lid%8 -> same XCD L2.
    const int lid = blockIdx.x;
    const int nl = (lid & 7) * 64 + (lid >> 3);
    const int b = nl >> 4;
    const int rb = nl & 15;
    const int rowBase = rb * 32;

    const float* pLre = Lre + (long)b * (N_SZ * N_SZ);
    const float* pLim = Lim + (long)b * (N_SZ * N_SZ);
    const long sB = (long)F_SZ * N_SZ;
    const short* pBrh = Brh + (long)b * sB;
    const short* pBrl = Brl + (long)b * sB;
    const short* pBih = HAS_BIM ? (Bih + (long)b * sB) : nullptr;
    const short* pBil = HAS_BIM ? (Bil + (long)b * sB) : nullptr;

    const int wn = t >> 6;                  // wave -> F/out columns 32*wn
    const int l = t & 63;
    const int r16 = l & 15, g = l >> 4;

    short8v SGN;
    #pragma unroll
    for (int j = 0; j < 8; ++j) SGN[j] = (short)0x8000;

    const f32x4 z4 = {0.f, 0.f, 0.f, 0.f};
    f32x4 accR[2][2], accI[2][2];
    #pragma unroll
    for (int i = 0; i < 2; ++i)
        #pragma unroll
        for (int j = 0; j < 2; ++j) { accR[i][j] = z4; accI[i][j] = z4; }

    // ---- stage 1: T = L @ h  (register-streamed, NO barriers) -----------
    // Per-lane row offsets (constant across K)
    const long aro0 = (long)(rowBase + r16) * 512 + g * 8;
    const long aro1 = (long)(rowBase + 16 + r16) * 512 + g * 8;
    const long bro0 = (long)(wn * 32 + r16) * 512 + g * 8;
    const long bro1 = (long)(wn * 32 + 16 + r16) * 512 + g * 8;

    #pragma unroll 2
    for (int kb = 0; kb < 512; kb += 32) {
        // B fragments: direct per-lane global loads (L2/L3-resident planes)
        short8v fB[2][4];
        {
            const long bo0 = bro0 + kb, bo1 = bro1 + kb;
            fB[0][0] = *(const short8v*)(pBrh + bo0);
            fB[1][0] = *(const short8v*)(pBrh + bo1);
            fB[0][1] = *(const short8v*)(pBrl + bo0);
            fB[1][1] = *(const short8v*)(pBrl + bo1);
            if (HAS_BIM) {
                fB[0][2] = *(const short8v*)(pBih + bo0);
                fB[1][2] = *(const short8v*)(pBih + bo1);
                fB[0][3] = *(const short8v*)(pBil + bo0);
                fB[1][3] = *(const short8v*)(pBil + bo1);
            }
        }
        // A fragments: load fp32, split to bf16 hi/lo in VALU
        short8v FA[2][4];
        {
            const long ao0 = aro0 + kb, ao1 = aro1 + kb;
            float4 x0 = *(const float4*)(pLre + ao0);
            float4 x1 = *(const float4*)(pLre + ao0 + 4);
            float4 y0 = *(const float4*)(pLim + ao0);
            float4 y1 = *(const float4*)(pLim + ao0 + 4);
            splitpack(x0, x1, FA[0][0], FA[0][1]);
            splitpack(y0, y1, FA[0][2], FA[0][3]);
            x0 = *(const float4*)(pLre + ao1);
            x1 = *(const float4*)(pLre + ao1 + 4);
            y0 = *(const float4*)(pLim + ao1);
            y1 = *(const float4*)(pLim + ao1 + 4);
            splitpack(x0, x1, FA[1][0], FA[1][1]);
            splitpack(y0, y1, FA[1][2], FA[1][3]);
        }
        #pragma unroll
        for (int tm = 0; tm < 2; ++tm) {
            const short8v nIh = FA[tm][2] ^ SGN;   // -Ai_hi
            const short8v nIl = FA[tm][3] ^ SGN;   // -Ai_lo
            #pragma unroll
            for (int tn = 0; tn < 2; ++tn) {
                accR[tm][tn] = MFMA16(FA[tm][0], fB[tn][0], accR[tm][tn]);
                accR[tm][tn] = MFMA16(FA[tm][1], fB[tn][0], accR[tm][tn]);
                accR[tm][tn] = MFMA16(FA[tm][0], fB[tn][1], accR[tm][tn]);
                accI[tm][tn] = MFMA16(FA[tm][2], fB[tn][0], accI[tm][tn]);
                accI[tm][tn] = MFMA16(FA[tm][3], fB[tn][0], accI[tm][tn]);
                accI[tm][tn] = MFMA16(FA[tm][2], fB[tn][1], accI[tm][tn]);
                if (HAS_BIM) {
                    accR[tm][tn] = MFMA16(nIh, fB[tn][2], accR[tm][tn]);
                    accR[tm][tn] = MFMA16(nIl, fB[tn][2], accR[tm][tn]);
                    accR[tm][tn] = MFMA16(nIh, fB[tn][3], accR[tm][tn]);
                    accI[tm][tn] = MFMA16(FA[tm][0], fB[tn][2], accI[tm][tn]);
                    accI[tm][tn] = MFMA16(FA[tm][1], fB[tn][2], accI[tm][tn]);
                    accI[tm][tn] = MFMA16(FA[tm][0], fB[tn][3], accI[tm][tn]);
                }
            }
        }
    }

    // ---- T tile -> LDS planes (only sync point) --------------------------
    #pragma unroll
    for (int tm = 0; tm < 2; ++tm)
        #pragma unroll
        for (int tn = 0; tn < 2; ++tn) {
            const int f = wn * 32 + tn * 16 + r16;
            #pragma unroll
            for (int rr = 0; rr < 4; ++rr) {
                const int node = tm * 16 + 4 * g + rr;
                short hs, ls;
                split1(accR[tm][tn][rr], hs, ls);
                Ts[0][node * 136 + f] = hs; Ts[1][node * 136 + f] = ls;
                split1(accI[tm][tn][rr], hs, ls);
                Ts[2][node * 136 + f] = hs; Ts[3][node * 136 + f] = ls;
            }
        }
    __syncthreads();

    // ---- stage 2: h' = crelu(T @ W) --------------------------------------
    f32x4 acc2R[2][2], acc2I[2][2];
    #pragma unroll
    for (int i = 0; i < 2; ++i)
        #pragma unroll
        for (int j = 0; j < 2; ++j) { acc2R[i][j] = z4; acc2I[i][j] = z4; }

    #pragma unroll
    for (int c = 0; c < 4; ++c) {
        short8v fW[2][4];
        #pragma unroll
        for (int tn = 0; tn < 2; ++tn) {
            const long wo = (long)(wn * 32 + tn * 16 + r16) * 128 + c * 32 + g * 8;
            fW[tn][0] = *(const short8v*)(Wrh + wo);
            fW[tn][1] = *(const short8v*)(Wrl + wo);
            fW[tn][2] = *(const short8v*)(Wih + wo);
            fW[tn][3] = *(const short8v*)(Wil + wo);
        }
        short8v fT[2][4];
        #pragma unroll
        for (int tm = 0; tm < 2; ++tm) {
            const int off = (tm * 16 + r16) * 136 + c * 32 + g * 8;
            #pragma unroll
            for (int p = 0; p < 4; ++p)
                fT[tm][p] = *(const short8v*)&Ts[p][off];
        }
        #pragma unroll
        for (int tm = 0; tm < 2; ++tm) {
            const short8v nIh = fT[tm][2] ^ SGN;
            const short8v nIl = fT[tm][3] ^ SGN;
            #pragma unroll
            for (int tn = 0; tn < 2; ++tn) {
                acc2R[tm][tn] = MFMA16(fT[tm][0], fW[tn][0], acc2R[tm][tn]);
                acc2R[tm][tn] = MFMA16(fT[tm][1], fW[tn][0], acc2R[tm][tn]);
                acc2R[tm][tn] = MFMA16(fT[tm][0], fW[tn][1], acc2R[tm][tn]);
                acc2R[tm][tn] = MFMA16(nIh, fW[tn][2], acc2R[tm][tn]);
                acc2R[tm][tn] = MFMA16(nIl, fW[tn][2], acc2R[tm][tn]);
                acc2R[tm][tn] = MFMA16(nIh, fW[tn][3], acc2R[tm][tn]);
                acc2I[tm][tn] = MFMA16(fT[tm][2], fW[tn][0], acc2I[tm][tn]);
                acc2I[tm][tn] = MFMA16(fT[tm][3], fW[tn][0], acc2I[tm][tn]);
                acc2I[tm][tn] = MFMA16(fT[tm][2], fW[tn][1], acc2I[tm][tn]);
                acc2I[tm][tn] = MFMA16(fT[tm][0], fW[tn][2], acc2I[tm][tn]);
                acc2I[tm][tn] = MFMA16(fT[tm][1], fW[tn][2], acc2I[tm][tn]);
                acc2I[tm][tn] = MFMA16(fT[tm][0], fW[tn][3], acc2I[tm][tn]);
            }
        }
    }

    // ---- epilogue --------------------------------------------------------
    if (LAST) {
        // crelu + node-sum over this block's 32 nodes, fused readout
        #pragma unroll
        for (int tn = 0; tn < 2; ++tn) {
            float sR = 0.f, sI = 0.f;
            #pragma unroll
            for (int tm = 0; tm < 2; ++tm)
                #pragma unroll
                for (int rr = 0; rr < 4; ++rr) {
                    float cr = acc2R[tm][tn][rr], ci = acc2I[tm][tn][rr];
                    if (cr < 0.f) { cr = 0.f; ci = 0.f; }
                    sR += cr; sI += ci;
                }
            // reduce across g (lanes l^16, l^32): sum over all 32 nodes
            sR += __shfl_xor(sR, 16); sR += __shfl_xor(sR, 32);
            sI += __shfl_xor(sI, 16); sI += __shfl_xor(sI, 32);
            if (g == 0) {
                const int f = wn * 32 + tn * 16 + r16;
                float* pp = part + ((long)b * 16 + rb) * 256;
                pp[f] = sR;
                pp[128 + f] = sI;
            }
        }
    } else {
        #pragma unroll
        for (int tm = 0; tm < 2; ++tm)
            #pragma unroll
            for (int tn = 0; tn < 2; ++tn) {
                const int out = wn * 32 + tn * 16 + r16;
                const int node0 = rowBase + tm * 16 + 4 * g;
                short4v rh, rl, ih, il;
                #pragma unroll
                for (int rr = 0; rr < 4; ++rr) {
                    float cr = acc2R[tm][tn][rr], ci = acc2I[tm][tn][rr];
                    if (cr < 0.f) { cr = 0.f; ci = 0.f; }
                    short hs, ls;
                    split1(cr, hs, ls); rh[rr] = hs; rl[rr] = ls;
                    split1(ci, hs, ls); ih[rr] = hs; il[rr] = ls;
                }
                const long base = ((long)b * 128 + out) * 512 + node0;
                *(short4v*)(Orh + base) = rh;
                *(short4v*)(Orl + base) = rl;
                *(short4v*)(Oih + base) = ih;
                *(short4v*)(Oil + base) = il;
            }
    }
}

// prep: blocks 0..255 transpose+split x; blocks 256..447 split W.
__global__ __launch_bounds__(256)
void prep_kernel(const float* __restrict__ x,
                 const float* __restrict__ Wr, const float* __restrict__ Wi,
                 short* __restrict__ Xh, short* __restrict__ Xl,
                 short* __restrict__ Wrh, short* __restrict__ Wrl,
                 short* __restrict__ Wih, short* __restrict__ Wil)
{
    const int t = threadIdx.x;
    if (blockIdx.x < 256) {
        __shared__ float XT[128][65];
        const int b = blockIdx.x >> 3, nc = blockIdx.x & 7;
        {
            const int nlan = t & 63, fc = t >> 6;
            const float* src = x + ((long)b * 512 + nc * 64 + nlan) * 128 + fc * 32;
            #pragma unroll
            for (int q = 0; q < 8; ++q) {
                float4 v = *(const float4*)(src + q * 4);
                XT[fc * 32 + q * 4 + 0][nlan] = v.x;
                XT[fc * 32 + q * 4 + 1][nlan] = v.y;
                XT[fc * 32 + q * 4 + 2][nlan] = v.z;
                XT[fc * 32 + q * 4 + 3][nlan] = v.w;
            }
        }
        __syncthreads();
        const int f = t >> 1, half = t & 1;
        short8v H[4], L[4];
        #pragma unroll
        for (int i = 0; i < 32; ++i) {
            short hs, ls;
            split1(XT[f][half * 32 + i], hs, ls);
            H[i >> 3][i & 7] = hs;
            L[i >> 3][i & 7] = ls;
        }
        const long base = ((long)b * 128 + f) * 512 + nc * 64 + half * 32;
        #pragma unroll
        for (int q = 0; q < 4; ++q) {
            *(short8v*)(Xh + base + q * 8) = H[q];
            *(short8v*)(Xl + base + q * 8) = L[q];
        }
    } else {
        const int idx = (blockIdx.x - 256) * 256 + t;   // 0..49151
        const int layer = idx >> 14;
        const int rem = idx & 16383;
        const int n = rem >> 7, k = rem & 127;
        const long src = ((long)layer * 128 + k) * 128 + n;
        const long dst = ((long)layer * 128 + n) * 128 + k;
        short hs, ls;
        split1(Wr[src], hs, ls); Wrh[dst] = hs; Wrl[dst] = ls;
        split1(Wi[src], hs, ls); Wih[dst] = hs; Wil[dst] = ls;
    }
}

// head: finish mean (sum 16 row-block partials), fc1+relu, fc2, softmax
__global__ __launch_bounds__(256)
void head_kernel(const float* __restrict__ part,
                 const float* __restrict__ w1, const float* __restrict__ b1,
                 const float* __restrict__ w2, const float* __restrict__ b2,
                 float* __restrict__ out)
{
    __shared__ float sf[256];
    __shared__ float sz[256];
    __shared__ float sl[16];
    const int b = blockIdx.x;
    const int t = threadIdx.x;

    float s = 0.f;
    #pragma unroll
    for (int rbk = 0; rbk < 16; ++rbk)
        s += part[((long)b * 16 + rbk) * 256 + t];
    sf[t] = s * (1.0f / 512.0f);
    __syncthreads();

    float acc = b1[t];
    const float* wrow = w1 + (long)t * 256;
    #pragma unroll 8
    for (int j = 0; j < 256; ++j) acc = fmaf(sf[j], wrow[j], acc);
    sz[t] = fmaxf(acc, 0.f);
    __syncthreads();

    if (t < 10) {
        float lg = b2[t];
        const float* w2r = w2 + (long)t * 256;
        #pragma unroll 8
        for (int j = 0; j < 256; ++j) lg = fmaf(sz[j], w2r[j], lg);
        sl[t] = lg;
    }
    __syncthreads();
    if (t == 0) {
        float m = sl[0];
        for (int c = 1; c < 10; ++c) m = fmaxf(m, sl[c]);
        float e[10]; float ss = 0.f;
        for (int c = 0; c < 10; ++c) { e[c] = expf(sl[c] - m); ss += e[c]; }
        const float inv = 1.f / ss;
        for (int c = 0; c < 10; ++c) out[b * 10 + c] = e[c] * inv;
    }
}

extern "C" void kernel_launch(void* const* d_in, const int* in_sizes, int n_in,
                              void* d_out, int out_size, void* d_ws, size_t ws_size,
                              hipStream_t stream)
{
    const float* x     = (const float*)d_in[0];   // [32,512,128]
    const float* Lre   = (const float*)d_in[1];   // [32,512,512]
    const float* Lim   = (const float*)d_in[2];
    const float* Wr    = (const float*)d_in[3];   // [3,128,128]
    const float* Wi    = (const float*)d_in[4];
    const float* fc1_w = (const float*)d_in[5];
    const float* fc1_b = (const float*)d_in[6];
    const float* fc2_w = (const float*)d_in[7];
    const float* fc2_b = (const float*)d_in[8];
    float* out = (float*)d_out;

    const long BNF = (long)B_SZ * N_SZ * F_SZ;    // 2,097,152
    short* h0 = (short*)d_ws;                     // [4][BNF] (planes rh,rl,ih,il)
    short* h1 = h0 + 4 * BNF;
    short* Wrh = h1 + 4 * BNF;                    // [3][128][128] planes
    short* Wrl = Wrh + 3 * 128 * 128;
    short* Wih = Wrl + 3 * 128 * 128;
    short* Wil = Wih + 3 * 128 * 128;
    float* part = (float*)(Wil + 3 * 128 * 128);  // [32*16][256]

    const long wsz = 128 * 128;

    prep_kernel<<<448, 256, 0, stream>>>(x, Wr, Wi, h0, h0 + BNF,
                                         Wrh, Wrl, Wih, Wil);

    // layer 0: h0(real x planes) -> h1
    fused_layer<0, 0><<<512, 256, 0, stream>>>(
        Lre, Lim, h0, h0 + BNF, nullptr, nullptr,
        Wrh, Wrl, Wih, Wil,
        h1, h1 + BNF, h1 + 2 * BNF, h1 + 3 * BNF, nullptr);
    // layer 1: h1 -> h0
    fused_layer<1, 0><<<512, 256, 0, stream>>>(
        Lre, Lim, h1, h1 + BNF, h1 + 2 * BNF, h1 + 3 * BNF,
        Wrh + wsz, Wrl + wsz, Wih + wsz, Wil + wsz,
        h0, h0 + BNF, h0 + 2 * BNF, h0 + 3 * BNF, nullptr);
    // layer 2: h0 -> fused readout partials
    fused_layer<1, 1><<<512, 256, 0, stream>>>(
        Lre, Lim, h0, h0 + BNF, h0 + 2 * BNF, h0 + 3 * BNF,
        Wrh + 2 * wsz, Wrl + 2 * wsz, Wih + 2 * wsz, Wil + 2 * wsz,
        nullptr, nullptr, nullptr, nullptr, part);

    head_kernel<<<B_SZ, 256, 0, stream>>>(part, fc1_w, fc1_b, fc2_w, fc2_b, out);
}